// Round 4
// baseline (14996.431 us; speedup 1.0000x reference)
//
#include <hip/hip_runtime.h>
#include <hip/hip_bf16.h>
#include <math.h>

#define V 32000
#define E 512
#define H 1024
#define SQ 128
#define T 100
#define NB 256
#define NT 256
#define GROWS 16    // 4096 gate rows / 256 blocks
#define FROWS 125   // 32000 fc rows / 256 blocks
#define NEG_BIG (-1e30f)

typedef unsigned int u32;
typedef unsigned long long u64;

struct WS {
  float gates[4*H];        // gate pre-activations for current step
  float h[H];              // hidden state (written by k_b block 0)
  float c[2][H];           // cell state, double-buffered by step parity
  float logits[V];         // raw logits of current step
  float pmax[NB];          // per-block max logit
  float psum[NB];          // per-block sum exp(logit - blockmax)
  u64   pkey[NB];          // per-block packed argmax key
};

__device__ __forceinline__ float wave_sum(float v){
  #pragma unroll
  for (int m = 32; m; m >>= 1) v += __shfl_xor(v, m, 64);
  return v;
}

__device__ __forceinline__ float dot4(float4 w, const float* v){
  return w.x*v[0] + w.y*v[1] + w.z*v[2] + w.w*v[3];
}

__global__ void __launch_bounds__(NT) k_init(const float* __restrict__ hn,
                                             const float* __restrict__ cn,
                                             WS* __restrict__ ws){
  int tid = threadIdx.x;
  for (int j = tid; j < H; j += NT){
    ws->h[j]    = hn[j];
    ws->c[0][j] = cn[j];
  }
  ws->pmax[tid] = NEG_BIG;
  ws->psum[tid] = 0.f;
  ws->pkey[tid] = 0ull;
}

// k_a(t): finalize step t-1 (logZ, logp writes, index, token decode), then gates for step t
__global__ void __launch_bounds__(NT) k_a(const float* __restrict__ emb,
                                          const float* __restrict__ W_ih,
                                          const float* __restrict__ W_hh,
                                          const float* __restrict__ b_ih,
                                          const float* __restrict__ b_hh,
                                          WS* __restrict__ ws,
                                          float* __restrict__ out,
                                          int t){
  __shared__ float redf[NT];
  __shared__ u64   redu[NT];
  int b = blockIdx.x, tid = threadIdx.x;
  int wv = tid >> 6, ln = tid & 63;
  int tok = 2;  // SOS

  if (t > 0){
    // global logZ + argmax from 256 per-block partials (redundantly per block)
    float mb = ws->pmax[tid];
    float sb = ws->psum[tid];
    u64   kb = ws->pkey[tid];
    redf[tid] = mb; redu[tid] = kb; __syncthreads();
    for (int o = 128; o; o >>= 1){
      if (tid < o){
        redf[tid] = fmaxf(redf[tid], redf[tid+o]);
        u64 a = redu[tid], c = redu[tid+o];
        redu[tid] = (a > c) ? a : c;
      }
      __syncthreads();
    }
    float m = redf[0];
    u64 key = redu[0];
    __syncthreads();
    redf[tid] = sb * expf(mb - m); __syncthreads();
    for (int o = 128; o; o >>= 1){ if (tid < o) redf[tid] += redf[tid+o]; __syncthreads(); }
    float logZ = m + logf(fmaxf(redf[0], 1e-30f));

    tok = (int)(~(u32)key);              // low 32 bits hold ~row
    if ((u32)tok >= (u32)V) tok = 2;     // defensive: never read OOB embedding

    if (tid < FROWS){
      int row = b*FROWS + tid;
      out[(size_t)(t-1)*V + row] = ws->logits[row] - logZ;
    }
    if (b == 0 && tid == 0)
      out[(size_t)T*V + (t-1)] = (float)tok;   // indices chunk, stored as f32
  }

  if (t < T){
    // preload lane slices of x = emb[tok] (8 elems) and h (16 elems), reused across rows
    float xv[8], hv[16];
    {
      const float4* xp = (const float4*)(emb + (size_t)tok*E) + ln*2;
      float4 x0 = xp[0], x1 = xp[1];
      xv[0]=x0.x; xv[1]=x0.y; xv[2]=x0.z; xv[3]=x0.w;
      xv[4]=x1.x; xv[5]=x1.y; xv[6]=x1.z; xv[7]=x1.w;
      const float4* hp = (const float4*)(ws->h) + ln*4;
      float4 h0 = hp[0], h1 = hp[1], h2 = hp[2], h3 = hp[3];
      hv[0]=h0.x; hv[1]=h0.y; hv[2]=h0.z; hv[3]=h0.w;
      hv[4]=h1.x; hv[5]=h1.y; hv[6]=h1.z; hv[7]=h1.w;
      hv[8]=h2.x; hv[9]=h2.y; hv[10]=h2.z; hv[11]=h2.w;
      hv[12]=h3.x; hv[13]=h3.y; hv[14]=h3.z; hv[15]=h3.w;
    }
    // wave wv handles 4 of the block's 16 gate rows
    for (int rl = wv*4; rl < wv*4 + 4; ++rl){
      int row = b*GROWS + rl;
      const float4* ap = (const float4*)(W_ih + (size_t)row*E) + ln*2;
      float4 a0 = ap[0], a1 = ap[1];
      const float4* wh = (const float4*)(W_hh + (size_t)row*H) + ln*4;
      float4 w0 = wh[0], w1 = wh[1], w2 = wh[2], w3 = wh[3];
      float acc = dot4(a0, xv) + dot4(a1, xv+4)
                + dot4(w0, hv) + dot4(w1, hv+4) + dot4(w2, hv+8) + dot4(w3, hv+12);
      acc = wave_sum(acc);
      if (ln == 0)
        ws->gates[row] = acc + b_ih[row] + b_hh[row];
    }
  }
}

// k_b(t): h2/c2 (redundant per block), scores+softmax+ctx (redundant), FC slice + partials
__global__ void __launch_bounds__(NT) k_b(const float* __restrict__ enc,
                                          const float* __restrict__ W_fc,
                                          const float* __restrict__ b_fc,
                                          WS* __restrict__ ws,
                                          int t){
  __shared__ float concat[2*H];   // [0,H) = h2, [H,2H) = ctx
  __shared__ float sc[SQ];
  __shared__ float pw[SQ];
  __shared__ float lg[128];
  __shared__ float redf[NT];
  __shared__ u64   redu[NT];
  int b = blockIdx.x, tid = threadIdx.x;
  int wv = tid >> 6, ln = tid & 63;

  // phase 1: LSTM cell update (every block redundantly; block 0 persists h,c)
  {
    float c2v[4], h2v[4];
    #pragma unroll
    for (int k = 0; k < 4; ++k){
      int j = tid + k*NT;
      float gi = ws->gates[j];
      float gf = ws->gates[H + j];
      float gg = ws->gates[2*H + j];
      float go = ws->gates[3*H + j];
      float co = ws->c[t & 1][j];
      float si = 1.f/(1.f + expf(-gi));
      float sf = 1.f/(1.f + expf(-gf));
      float tg = tanhf(gg);
      float so = 1.f/(1.f + expf(-go));
      float cn = sf*co + si*tg;
      float hn = so*tanhf(cn);
      c2v[k] = cn; h2v[k] = hn;
      concat[j] = hn;
    }
    if (b == 0){
      #pragma unroll
      for (int k = 0; k < 4; ++k){
        int j = tid + k*NT;
        ws->c[(t+1) & 1][j] = c2v[k];
        ws->h[j] = h2v[k];
      }
    }
  }
  __syncthreads();

  // phase 2: attention scores = enc @ h2 (wave per row, 32 rows per wave)
  {
    float hv[16];
    #pragma unroll
    for (int k = 0; k < 16; ++k) hv[k] = concat[ln*16 + k];
    for (int s = wv*32; s < wv*32 + 32; ++s){
      const float4* ep = (const float4*)(enc + (size_t)s*H) + ln*4;
      float4 e0 = ep[0], e1 = ep[1], e2 = ep[2], e3 = ep[3];
      float acc = dot4(e0, hv) + dot4(e1, hv+4) + dot4(e2, hv+8) + dot4(e3, hv+12);
      acc = wave_sum(acc);
      if (ln == 0) sc[s] = acc;
    }
  }
  __syncthreads();

  // phase 3: softmax over 128 scores
  {
    float v = (tid < SQ) ? sc[tid] : NEG_BIG;
    redf[tid] = v; __syncthreads();
    for (int o = 128; o; o >>= 1){ if (tid < o) redf[tid] = fmaxf(redf[tid], redf[tid+o]); __syncthreads(); }
    float m = redf[0]; __syncthreads();
    float e = (tid < SQ) ? expf(v - m) : 0.f;
    redf[tid] = e; __syncthreads();
    for (int o = 128; o; o >>= 1){ if (tid < o) redf[tid] += redf[tid+o]; __syncthreads(); }
    float S = redf[0];
    if (tid < SQ) pw[tid] = e / S;
  }
  __syncthreads();

  // phase 4: ctx[j] = sum_s pw[s] * enc[s][j]; thread handles 4 contiguous cols
  {
    float a0=0.f, a1=0.f, a2=0.f, a3=0.f;
    const float4* eb = (const float4*)enc + tid;   // cols [tid*4, tid*4+4)
    for (int s = 0; s < SQ; ++s){
      float4 e = eb[(size_t)s*(H/4)];
      float w = pw[s];
      a0 += w*e.x; a1 += w*e.y; a2 += w*e.z; a3 += w*e.w;
    }
    concat[H + tid*4 + 0] = a0;
    concat[H + tid*4 + 1] = a1;
    concat[H + tid*4 + 2] = a2;
    concat[H + tid*4 + 3] = a3;
  }
  __syncthreads();

  // phase 5: FC rows (wave per row; concat slice in registers to avoid LDS conflicts)
  {
    float cv[32];
    #pragma unroll
    for (int k = 0; k < 8; ++k)
      #pragma unroll
      for (int m = 0; m < 4; ++m)
        cv[k*4 + m] = concat[k*256 + ln*4 + m];

    for (int l = wv; l < FROWS; l += 4){
      int row = b*FROWS + l;
      const float4* wp = (const float4*)(W_fc + (size_t)row*2048) + ln;
      float acc = 0.f;
      #pragma unroll
      for (int k = 0; k < 8; ++k){
        float4 w = wp[(size_t)k*64];
        acc += dot4(w, cv + k*4);
      }
      acc = wave_sum(acc);
      if (ln == 0){
        acc += b_fc[row];
        ws->logits[row] = acc;
        lg[l] = acc;
      }
    }
  }
  __syncthreads();

  // phase 6: block-local max / sumexp / packed argmax key
  {
    float v = (tid < FROWS) ? lg[tid] : NEG_BIG;
    redf[tid] = v; __syncthreads();
    for (int o = 128; o; o >>= 1){ if (tid < o) redf[tid] = fmaxf(redf[tid], redf[tid+o]); __syncthreads(); }
    float mb = redf[0]; __syncthreads();
    float e = (tid < FROWS) ? expf(v - mb) : 0.f;
    redf[tid] = e; __syncthreads();
    for (int o = 128; o; o >>= 1){ if (tid < o) redf[tid] += redf[tid+o]; __syncthreads(); }
    float sb = redf[0];

    u64 key = 0ull;
    if (tid < FROWS){
      u32 u = __float_as_uint(v);
      u32 srt = (u >> 31) ? ~u : (u | 0x80000000u);   // monotone float->uint map
      key = ((u64)srt << 32) | (u32)(~(u32)(b*FROWS + tid));  // ties -> smaller row wins
    }
    redu[tid] = key; __syncthreads();
    for (int o = 128; o; o >>= 1){ if (tid < o){ u64 a = redu[tid], c = redu[tid+o]; redu[tid] = a > c ? a : c; } __syncthreads(); }

    if (tid == 0){
      ws->pmax[b] = mb;
      ws->psum[b] = sb;
      ws->pkey[b] = redu[0];
    }
  }
}

extern "C" void kernel_launch(void* const* d_in, const int* in_sizes, int n_in,
                              void* d_out, int out_size, void* d_ws, size_t ws_size,
                              hipStream_t stream){
  const float* hn   = (const float*)d_in[0];
  const float* cn   = (const float*)d_in[1];
  const float* enc  = (const float*)d_in[2];
  const float* emb  = (const float*)d_in[3];
  const float* W_ih = (const float*)d_in[4];
  const float* W_hh = (const float*)d_in[5];
  const float* b_ih = (const float*)d_in[6];
  const float* b_hh = (const float*)d_in[7];
  const float* W_fc = (const float*)d_in[8];
  const float* b_fc = (const float*)d_in[9];
  float* out = (float*)d_out;
  WS* ws = (WS*)d_ws;
  if (ws_size < sizeof(WS)) return;  // needs ~160 KB

  k_init<<<1, NT, 0, stream>>>(hn, cn, ws);
  for (int t = 0; t <= T; ++t){
    k_a<<<NB, NT, 0, stream>>>(emb, W_ih, W_hh, b_ih, b_hh, ws, out, t);
    if (t < T) k_b<<<NB, NT, 0, stream>>>(enc, W_fc, b_fc, ws, t);
  }
}